// Round 4
// baseline (209.633 us; speedup 1.0000x reference)
//
#include <hip/hip_runtime.h>

// Q: (2, 5120, 5120) fp32, block-tridiagonal in 1024-blocks.
// Pipeline (3 launches):
//   decode_kernel : params -> Ac[i][p][9]  (A-row stencil coeffs, i=b*4+(t-1))
//   tables_kernel : one THREAD per table entry:
//                     offd[i][p][9]  = -0.5*(invM+invM^T) entries
//                     diag[j][p][25] = B0^T B0+I+.05 (rb=0) or
//                                      0.5*(M2+M2^T)+I?+.05 (rb>=1), j=b*5+rb
//   fill_kernel   : one block per (row,b); each thread streams 5 float4s
//                   (the full 20 KB row) with O(1) table lookups.

#define AC_OFF   0
#define OFFD_OFF 73728           // 8*1024*9
#define DIAG_OFF 147456          // OFFD_OFF + 8*1024*9
// total ws floats: 147456 + 10*1024*25 = 403456 (~1.6 MB)

__device__ __forceinline__ float softplus10(float x) {
  float z = 10.f * x;
  return (fmaxf(z, 0.f) + log1pf(expf(-fabsf(z)))) * 0.1f;
}

__global__ __launch_bounds__(256) void decode_kernel(
    const float* __restrict__ P0, float* __restrict__ Ac) {
  int gid = blockIdx.x * 256 + threadIdx.x;
  if (gid >= 8 * 1024) return;
  int i = gid >> 10;
  int p = gid & 1023;
  int b = i >> 2;
  int t = (i & 3) + 1;
  const float* P = P0 + b * 35 * 1024;

  // kappa/m: reference's raw-reshape axis mixing (q = p*5 + t)
  int qq = p * 5 + t;
  int c  = qq >> 10;
  int r  = qq & 1023;
  float kap = softplus10(P[(0 + c) * 1024 + r]);
  float m1  = P[(5 + c) * 1024 + r];
  float m2  = P[(10 + c) * 1024 + r];

  // gamma/vx/vy: proper transpose layout
  float g  = softplus10(P[(15 + t) * 1024 + p]);
  float vx = P[(20 + t) * 1024 + p];
  float vy = P[(25 + t) * 1024 + p];

  float H11 = g + vx * vx;
  float H22 = g + vy * vy;
  float H12 = vx * vy;

  float co[9];
  co[4] = kap * kap + 2.f * H11 + 2.f * H22;
  co[5] = -H11 + 0.5f * m1;
  co[3] = -H11 - 0.5f * m1;
  co[7] = -H22 + 0.5f * m2;
  co[1] = -H22 - 0.5f * m2;
  co[8] = -0.5f * H12;
  co[0] = -0.5f * H12;
  co[2] =  0.5f * H12;
  co[6] =  0.5f * H12;

  int px = p & 31, py = p >> 5;
  #pragma unroll
  for (int o = 0; o < 9; o++) {
    const int dx = o % 3 - 1, dy = o / 3 - 1;
    int nx = px + dx, ny = py + dy;
    bool valid = (nx >= 0) & (nx < 32) & (ny >= 0) & (ny < 32);
    Ac[(i * 1024 + p) * 9 + o] = (o == 4) ? co[4] : (valid ? co[o] : 0.f);
  }
}

__device__ __forceinline__ float m2e(const float* __restrict__ Ac, int i, int p, int q) {
  int px = p & 31, py = p >> 5, qx = q & 31, qy = q >> 5;
  float s = 0.f;
  #pragma unroll
  for (int o = 0; o < 9; o++) {
    const int dx = o % 3 - 1, dy = o / 3 - 1;
    int kx = px + dx, ky = py + dy;
    if (kx < 0 || kx > 31 || ky < 0 || ky > 31) continue;
    int k = ky * 32 + kx;
    float a = Ac[(i * 1024 + p) * 9 + o] + (o == 4 ? 1.f : 0.f);
    int ddx = qx - kx, ddy = qy - ky;
    if (ddx < -1 || ddx > 1 || ddy < -1 || ddy > 1) continue;
    float bb = Ac[(i * 1024 + k) * 9 + (ddy + 1) * 3 + (ddx + 1)] + (k == q ? 1.f : 0.f);
    s += a * bb;
  }
  return s;
}

__device__ __forceinline__ float btb(const float* __restrict__ Ac, int i0, int p, int q) {
  int px = p & 31, py = p >> 5, qx = q & 31, qy = q >> 5;
  float s = 0.f;
  #pragma unroll
  for (int o = 0; o < 9; o++) {
    const int dx = o % 3 - 1, dy = o / 3 - 1;
    int kx = px + dx, ky = py + dy;
    if (kx < 0 || kx > 31 || ky < 0 || ky > 31) continue;
    int k = ky * 32 + kx;
    float bkp = Ac[(i0 * 1024 + k) * 9 + (8 - o)];
    int ddx = qx - kx, ddy = qy - ky;
    if (ddx < -1 || ddx > 1 || ddy < -1 || ddy > 1) continue;
    float bkq = Ac[(i0 * 1024 + k) * 9 + (ddy + 1) * 3 + (ddx + 1)];
    s += bkp * bkq;
  }
  return s;
}

// One thread per table entry: [0,73728) -> offd, [73728, 329728) -> diag.
__global__ __launch_bounds__(256) void tables_kernel(float* __restrict__ ws) {
  const float* Ac = ws + AC_OFF;
  int gid = blockIdx.x * 256 + threadIdx.x;
  if (gid < 73728) {
    // offd[i][p][o] = -0.5*(invM[p,q] + invM[q,p])
    int i = gid / 9216;
    int rem = gid - i * 9216;
    int p = rem / 9;
    int o = rem - p * 9;
    int px = p & 31, py = p >> 5;
    int dx = o % 3 - 1, dy = o / 3 - 1;
    float v = 0.f;
    if (o == 4) {
      v = -(Ac[(i * 1024 + p) * 9 + 4] + 1.f);
    } else {
      int nx = px + dx, ny = py + dy;
      if (nx >= 0 && nx < 32 && ny >= 0 && ny < 32) {
        int q = ny * 32 + nx;
        v = -0.5f * (Ac[(i * 1024 + p) * 9 + o] + Ac[(i * 1024 + q) * 9 + (8 - o)]);
      }
    }
    ws[OFFD_OFF + gid] = v;
  } else {
    int e = gid - 73728;
    if (e >= 256000) return;
    // diag[j][p][w], j = b*5+rb, w = (dy+2)*5+(dx+2)
    int j = e / 25600;
    int rem = e - j * 25600;
    int p = rem / 25;
    int w = rem - p * 25;
    int b = j / 5, rb = j - b * 5;
    int px = p & 31, py = p >> 5;
    int dx = w % 5 - 2, dy = w / 5 - 2;
    int nx = px + dx, ny = py + dy;
    float v = 0.f;
    if (nx >= 0 && nx < 32 && ny >= 0 && ny < 32) {
      int q = ny * 32 + nx;
      if (rb == 0) {
        v = btb(Ac, b * 4, p, q) + (p == q ? 1.05f : 0.f);
      } else {
        int i = b * 4 + rb - 1;
        float diagAdd = (rb <= 3 ? 1.05f : 0.05f);
        v = 0.5f * (m2e(Ac, i, p, q) + m2e(Ac, i, q, p)) + (p == q ? diagAdd : 0.f);
      }
    }
    ws[DIAG_OFF + e] = v;
  }
}

// grid (5120 rows, 2 batches) x 256 threads; each thread writes 5 float4s
// covering the full 5120-float row. Chunk branches are wave-uniform.
__global__ __launch_bounds__(256) void fill_kernel(
    const float* __restrict__ ws, float4* __restrict__ out) {
  const int row = blockIdx.x;   // 0..5119
  const int b   = blockIdx.y;   // 0..1
  const int tx  = threadIdx.x;  // 0..255
  const int rb  = row >> 10;
  const int p   = row & 1023;

  const int q0  = tx * 4;
  const int qy  = q0 >> 5;
  const int qx0 = q0 & 31;
  const int px  = p & 31, py = p >> 5;
  const int dy  = qy - py;

  // hoisted table row pointers
  const float* Dp = ws + DIAG_OFF + ((b * 5 + rb) * 1024 + p) * 25;
  const long rowbase = ((long)b * 5120 + row) * 1280 + tx;

  float4 vs[5];
  #pragma unroll
  for (int cb = 0; cb < 5; cb++) {
    float rr[4] = {0.f, 0.f, 0.f, 0.f};
    const int d = cb - rb;
    if (d == 0) {
      if (dy >= -2 && dy <= 2) {
        const float* t = Dp + (dy + 2) * 5 + 2 - px;
        #pragma unroll
        for (int jj = 0; jj < 4; jj++) {
          int dx = qx0 + jj - px;
          if (dx >= -2 && dx <= 2) rr[jj] = t[qx0 + jj];
        }
      }
    } else if (d == 1 || d == -1) {
      if (dy >= -1 && dy <= 1) {
        const int i = b * 4 + (d > 0 ? rb : cb);
        const float* t = ws + OFFD_OFF + ((i * 1024 + p) * 9 + (dy + 1) * 3 + 1) - px;
        #pragma unroll
        for (int jj = 0; jj < 4; jj++) {
          int dx = qx0 + jj - px;
          if (dx >= -1 && dx <= 1) rr[jj] = t[qx0 + jj];
        }
      }
    }
    vs[cb] = make_float4(rr[0], rr[1], rr[2], rr[3]);
  }
  #pragma unroll
  for (int cb = 0; cb < 5; cb++) {
    out[rowbase + cb * 256] = vs[cb];
  }
}

extern "C" void kernel_launch(void* const* d_in, const int* in_sizes, int n_in,
                              void* d_out, int out_size, void* d_ws, size_t ws_size,
                              hipStream_t stream) {
  const float* params = (const float*)d_in[0];  // (2, 35, 32, 32) fp32
  float* ws = (float*)d_ws;                     // ~1.6 MB used
  float4* out = (float4*)d_out;                 // (2, 5120, 5120) fp32

  decode_kernel<<<32, 256, 0, stream>>>(params, ws + AC_OFF);
  tables_kernel<<<1288, 256, 0, stream>>>(ws);  // 329728 entry-threads
  dim3 grid(5120, 2);
  fill_kernel<<<grid, 256, 0, stream>>>(ws, out);
}